// Round 6
// baseline (319.391 us; speedup 1.0000x reference)
//
#include <hip/hip_runtime.h>

#define N 8192
#define CIN 256
#define C8 32
#define QBLK 128
#define KVB 64
#define L2E 1.4426950408889634f

typedef __attribute__((ext_vector_type(8))) short short8;   // 8 x bf16 MFMA frag
typedef __attribute__((ext_vector_type(4))) float f32x4;
typedef __attribute__((ext_vector_type(4))) float float4_;
typedef __attribute__((ext_vector_type(4))) unsigned short ushort4_;
typedef __attribute__((ext_vector_type(2))) unsigned uint2_;

// ---- ws layout (ushort units) ----
#define OFF_QTA 0u
#define OFF_KTA 262144u
#define OFF_QTB 524288u
#define OFF_KTB 786432u
#define OFF_VA  1048576u
#define OFF_VB  3145728u
#define PROJ_USHORTS 5242880u
// Wb (640x256 bf16) overlaps accb start: castW->proj read it, attn then clobbers.
// accb bf16 [128*SP blocks][256][128]; Lpart f32 [128*SP][128] after accb.

__device__ __forceinline__ unsigned short f2bf(float f) {
    unsigned u = __builtin_bit_cast(unsigned, f);
    u += 0x7fffu + ((u >> 16) & 1u);           // RNE
    return (unsigned short)(u >> 16);
}
__device__ __forceinline__ unsigned packbf2(float a, float b) {
    return (unsigned)f2bf(a) | ((unsigned)f2bf(b) << 16);
}
__device__ __forceinline__ float bf2f(unsigned short u) {
    return __builtin_bit_cast(float, (unsigned)u << 16);
}

// ---------------- castW: f32 W -> bf16 Wb[640][256], Q rows scaled by log2e ----------------
__global__ __launch_bounds__(256) void castw_kernel(
    const float* __restrict__ WqA, const float* __restrict__ WkA, const float* __restrict__ WvA,
    const float* __restrict__ WqB, const float* __restrict__ WkB, const float* __restrict__ WvB,
    unsigned short* __restrict__ Wb)
{
    const int idx = blockIdx.x * 256 + threadIdx.x;
    const int e = idx * 4;
    const int r = e >> 8;
    const float* src; int rel;
    if (r < 32)       { src = WqA; rel = e; }
    else if (r < 64)  { src = WkA; rel = e - 32 * 256; }
    else if (r < 320) { src = WvA; rel = e - 64 * 256; }
    else if (r < 352) { src = WqB; rel = e - 320 * 256; }
    else if (r < 384) { src = WkB; rel = e - 352 * 256; }
    else              { src = WvB; rel = e - 384 * 256; }
    const float sc = (r < 32 || (r >= 320 && r < 352)) ? L2E : 1.0f;
    float4_ v = *(const float4_*)(src + rel);
    ushort4_ o;
    o.x = f2bf(v.x * sc); o.y = f2bf(v.y * sc); o.z = f2bf(v.z * sc); o.w = f2bf(v.w * sc);
    *(ushort4_*)(Wb + e) = o;
}

// ---------------- projection via MFMA ----------------
// grid 256 (n-tiles of 32), 512 thr (8 waves). Wave w owns o-tiles [5w,5w+5) of 40.
// LDS xT[32 n][256 c] bf16, byte-XOR swizzled: byte = n*512 + (2c ^ ((n&7)<<4)).
// Q/K: mfma(wf,xf) -> D[o][n], store qt[n][o] packed b64 along o.
// V:   mfma(xf,wf) -> D[n][o], store V[o][n] packed b64 along n.
__global__ __launch_bounds__(512) void proj_kernel(
    const float* __restrict__ x, const unsigned short* __restrict__ Wb,
    const float* __restrict__ bqA, const float* __restrict__ bkA, const float* __restrict__ bvA,
    const float* __restrict__ bqB, const float* __restrict__ bkB, const float* __restrict__ bvB,
    unsigned short* __restrict__ ws)
{
    __shared__ __align__(16) unsigned short xT[32 * 256];   // 16 KB

    const int tid = threadIdx.x;
    const int w = tid >> 6, l = tid & 63, g = l >> 4, lc = l & 15;
    const int n0 = blockIdx.x * 32;

    #pragma unroll
    for (int r = 0; r < 4; ++r) {
        const int flat4 = r * 512 + tid;
        const int c = flat4 >> 3, nl = (flat4 & 7) * 4;
        float4_ v = *(const float4_*)(x + (size_t)c * N + n0 + nl);
        #pragma unroll
        for (int e = 0; e < 4; ++e) {
            const int nn = nl + e;
            const int byte = nn * 512 + ((2 * c) ^ ((nn & 7) << 4));
            *(unsigned short*)((char*)xT + byte) = f2bf(v[e]);
        }
    }
    __syncthreads();

    f32x4 acc[5][2];
    #pragma unroll
    for (int i = 0; i < 5; ++i)
        #pragma unroll
        for (int ns = 0; ns < 2; ++ns) acc[i][ns] = (f32x4){0.f, 0.f, 0.f, 0.f};

    for (int c0 = 0; c0 < 256; c0 += 32) {
        short8 xf[2];
        #pragma unroll
        for (int ns = 0; ns < 2; ++ns) {
            const int byte = (ns * 16 + lc) * 512 + ((2 * (c0 + 8 * g)) ^ ((lc & 7) << 4));
            xf[ns] = *(const short8*)((const char*)xT + byte);
        }
        #pragma unroll
        for (int i = 0; i < 5; ++i) {
            const int ot = w * 5 + i;
            const short8 wf = *(const short8*)(Wb + (size_t)(ot * 16 + lc) * 256 + c0 + 8 * g);
            const bool isV = (ot >= 4 && ot < 20) || (ot >= 24);
            #pragma unroll
            for (int ns = 0; ns < 2; ++ns)
                acc[i][ns] = isV
                    ? __builtin_amdgcn_mfma_f32_16x16x32_bf16(xf[ns], wf, acc[i][ns], 0, 0, 0)
                    : __builtin_amdgcn_mfma_f32_16x16x32_bf16(wf, xf[ns], acc[i][ns], 0, 0, 0);
        }
    }

    #pragma unroll
    for (int i = 0; i < 5; ++i) {
        const int ot = w * 5 + i;
        const float* bias; unsigned short* dst; int orelm; bool isV = false; float bsc = 1.0f;
        if (ot < 2)       { bias = bqA; dst = ws + OFF_QTA; orelm = ot * 16;        bsc = L2E; }
        else if (ot < 4)  { bias = bkA; dst = ws + OFF_KTA; orelm = (ot - 2) * 16; }
        else if (ot < 20) { bias = bvA; dst = ws + OFF_VA;  orelm = (ot - 4) * 16;  isV = true; }
        else if (ot < 22) { bias = bqB; dst = ws + OFF_QTB; orelm = (ot - 20) * 16; bsc = L2E; }
        else if (ot < 24) { bias = bkB; dst = ws + OFF_KTB; orelm = (ot - 22) * 16; }
        else              { bias = bvB; dst = ws + OFF_VB;  orelm = (ot - 24) * 16; isV = true; }

        if (isV) {
            // D[row=n=4g+ii][col=o=lc]: pack ii along n
            const float b = bias[orelm + lc];
            #pragma unroll
            for (int ns = 0; ns < 2; ++ns) {
                ushort4_ pk;
                pk.x = f2bf(acc[i][ns][0] + b); pk.y = f2bf(acc[i][ns][1] + b);
                pk.z = f2bf(acc[i][ns][2] + b); pk.w = f2bf(acc[i][ns][3] + b);
                *(ushort4_*)(dst + (size_t)(orelm + lc) * N + n0 + ns * 16 + 4 * g) = pk;
            }
        } else {
            // D[row=o=4g+ii][col=n=lc]: pack ii along o
            #pragma unroll
            for (int ns = 0; ns < 2; ++ns) {
                ushort4_ pk;
                #pragma unroll
                for (int ii = 0; ii < 4; ++ii)
                    pk[ii] = f2bf(acc[i][ns][ii] + bias[orelm + 4 * g + ii] * bsc);
                *(ushort4_*)(dst + (size_t)(n0 + ns * 16 + lc) * C8 + orelm + 4 * g) = pk;
            }
        }
    }
}

// ---------------- fused flash-attention v3 ----------------
// grid 2*64*SP (SP=2 -> 256 = 1 block/CU), 512 thr (8 waves). QBLK=128.
// Wave w: S^T+softmax for cols [16w,16w+16); PV cells ct in [4(w>>1),+4) x cj in [4(w&1),+4).
// V via global->register (no LDS), double-buffered. P via LDS, swizzled, dbuf, 1 barrier/step.
__global__ __launch_bounds__(512) void attn_kernel(
    const unsigned short* __restrict__ ws,
    unsigned short* __restrict__ accb,
    float* __restrict__ Lpart,
    int SP)
{
    __shared__ __align__(16) unsigned short Pl[2][QBLK * KVB];   // 2 x 16 KB, [q][m] swizzled

    const int tid = threadIdx.x;
    const int w = tid >> 6, l = tid & 63, g = l >> 4, lc = l & 15;
    const int bid = blockIdx.x;
    const int dir = bid & 1;            // 1: (QA,KB,VB)->task1@0 ; 0: (QB,KA,VA)->task2@CIN*N
    const int qb  = (bid >> 1) & 63;
    const int sp  = bid >> 7;
    const int mlen = N / SP, m_base = sp * mlen, NS = mlen / KVB;

    const unsigned short* qt = ws + (dir ? OFF_QTA : OFF_QTB);
    const unsigned short* kt = ws + (dir ? OFF_KTB : OFF_KTA);
    const unsigned short* V  = ws + (dir ? OFF_VB  : OFF_VA);

    const int q0  = qb * QBLK;
    const int myq = w * 16 + lc;                 // this lane's softmax col (local)
    const int ct0 = (w >> 1) * 4;                // 4 channel-tiles
    const int cj0 = (w & 1) * 4;                 // 4 col-tiles
    const int sw7 = lc & 7;

    const short8 qf = *(const short8*)(qt + (size_t)(q0 + myq) * C8 + 8 * g);

    short8 kf[4], kfn[4], vf[4][2], vfn[4][2];
    #pragma unroll
    for (int t = 0; t < 4; ++t)
        kf[t] = *(const short8*)(kt + (size_t)(m_base + 16 * t + lc) * C8 + 8 * g);
    #pragma unroll
    for (int u = 0; u < 4; ++u)
        #pragma unroll
        for (int kc = 0; kc < 2; ++kc)
            vf[u][kc] = *(const short8*)(V + (size_t)((ct0 + u) * 16 + lc) * N + m_base + kc * 32 + 8 * g);

    f32x4 acc[4][4];   // [j][u]: D[q][c] (PV as mfma(pf, vf))
    #pragma unroll
    for (int j = 0; j < 4; ++j)
        #pragma unroll
        for (int u = 0; u < 4; ++u) acc[j][u] = (f32x4){0.f, 0.f, 0.f, 0.f};
    float Lr = 0.f;

    #pragma unroll 2
    for (int s = 0; s < NS; ++s) {
        const int m0 = m_base + s * KVB;
        const int pb = s & 1;
        const bool more = (s + 1 < NS);

        // prefetch next K/V frags (global, consumed next step)
        if (more) {
            #pragma unroll
            for (int t = 0; t < 4; ++t)
                kfn[t] = *(const short8*)(kt + (size_t)(m0 + KVB + 16 * t + lc) * C8 + 8 * g);
            #pragma unroll
            for (int u = 0; u < 4; ++u)
                #pragma unroll
                for (int kc = 0; kc < 2; ++kc)
                    vfn[u][kc] = *(const short8*)(V + (size_t)((ct0 + u) * 16 + lc) * N + m0 + KVB + kc * 32 + 8 * g);
        }

        // ---- S phase: S^T = mfma(K,Q); P = exp2(S) (log2e folded into Wq/bq) ----
        f32x4 sv[4];
        #pragma unroll
        for (int t = 0; t < 4; ++t)
            sv[t] = __builtin_amdgcn_mfma_f32_16x16x32_bf16(kf[t], qf, (f32x4){0.f,0.f,0.f,0.f}, 0, 0, 0);

        #pragma unroll
        for (int t = 0; t < 4; ++t) {
            float p0 = __builtin_amdgcn_exp2f(sv[t][0]);
            float p1 = __builtin_amdgcn_exp2f(sv[t][1]);
            float p2 = __builtin_amdgcn_exp2f(sv[t][2]);
            float p3 = __builtin_amdgcn_exp2f(sv[t][3]);
            Lr += (p0 + p1) + (p2 + p3);
            uint2_ u2; u2.x = packbf2(p0, p1); u2.y = packbf2(p2, p3);
            // m = 16t+4g+i -> chunk 2t+(g>>1), half (g&1); swizzle chunk by q&7
            const int byte = myq * 128 + (((2 * t + (g >> 1)) ^ sw7) << 4) + ((g & 1) << 3);
            *(uint2_*)((char*)Pl[pb] + byte) = u2;
        }

        __syncthreads();   // P[pb] visible to all waves

        // ---- PV phase: acc[q][c] += P^T(as A) x V(as B) ----
        __builtin_amdgcn_s_setprio(1);
        #pragma unroll
        for (int j = 0; j < 4; ++j) {
            const int q = (cj0 + j) * 16 + lc;
            const short8 pf0 = *(const short8*)((const char*)Pl[pb] + q * 128 + ((g ^ sw7) << 4));
            const short8 pf1 = *(const short8*)((const char*)Pl[pb] + q * 128 + (((4 + g) ^ sw7) << 4));
            #pragma unroll
            for (int u = 0; u < 4; ++u) {
                acc[j][u] = __builtin_amdgcn_mfma_f32_16x16x32_bf16(pf0, vf[u][0], acc[j][u], 0, 0, 0);
                acc[j][u] = __builtin_amdgcn_mfma_f32_16x16x32_bf16(pf1, vf[u][1], acc[j][u], 0, 0, 0);
            }
        }
        __builtin_amdgcn_s_setprio(0);

        if (more) {
            #pragma unroll
            for (int t = 0; t < 4; ++t) kf[t] = kfn[t];
            #pragma unroll
            for (int u = 0; u < 4; ++u)
                #pragma unroll
                for (int kc = 0; kc < 2; ++kc) vf[u][kc] = vfn[u][kc];
        }
    }

    // ---- epilogue: store bf16 partials [q][c] -> accb[c][q] packed along q ----
    Lr += __shfl_xor(Lr, 16);
    Lr += __shfl_xor(Lr, 32);

    const size_t blk = (size_t)(dir * 64 + qb) * SP + sp;
    unsigned short* ab = accb + blk * (size_t)(CIN * QBLK);
    #pragma unroll
    for (int j = 0; j < 4; ++j)
        #pragma unroll
        for (int u = 0; u < 4; ++u) {
            const int c = (ct0 + u) * 16 + lc;
            const int qloc = (cj0 + j) * 16 + 4 * g;
            ushort4_ pk;
            pk.x = f2bf(acc[j][u][0]); pk.y = f2bf(acc[j][u][1]);
            pk.z = f2bf(acc[j][u][2]); pk.w = f2bf(acc[j][u][3]);
            *(ushort4_*)(ab + (size_t)c * QBLK + qloc) = pk;
        }
    if (l < 16) Lpart[blk * QBLK + w * 16 + l] = Lr;
}

// ---------------- combine: out = gamma * (sum acc)/(sum L) + x ----------------
__global__ __launch_bounds__(256) void combine_kernel(
    const float* __restrict__ x,
    const unsigned short* __restrict__ accb,
    const float* __restrict__ Lpart,
    const float* __restrict__ gammaA, const float* __restrict__ gammaB,
    float* __restrict__ out, int SP)
{
    const int tid = blockIdx.x * 256 + threadIdx.x;    // 2^19 threads x 8 elems
    const int nl0 = (tid & 15) * 8;
    const int qb  = (tid >> 4) & 63;
    const int c   = (tid >> 10) & 255;
    const int dir = (tid >> 18) & 1;

    const size_t bb = (size_t)(dir * 64 + qb) * SP;
    float s[8], Ls[8];
    #pragma unroll
    for (int e = 0; e < 8; ++e) { s[e] = 0.f; Ls[e] = 0.f; }

    for (int sp = 0; sp < SP; ++sp) {
        const unsigned short* ap = accb + (bb + sp) * (size_t)(CIN * QBLK) + (size_t)c * QBLK + nl0;
        const short8 av = *(const short8*)ap;
        const float* lp = Lpart + (bb + sp) * QBLK + nl0;
        #pragma unroll
        for (int e = 0; e < 8; ++e) {
            s[e]  += bf2f((unsigned short)av[e]);
            Ls[e] += lp[e];
        }
    }

    const float gamma = dir ? gammaA[0] : gammaB[0];
    const size_t off = (size_t)c * N + qb * QBLK + nl0;
    const float* xp = x + off;
    float* op = out + (dir ? 0 : (size_t)CIN * N) + off;
    #pragma unroll
    for (int e = 0; e < 8; ++e) op[e] = gamma * s[e] / Ls[e] + xp[e];
}

extern "C" void kernel_launch(void* const* d_in, const int* in_sizes, int n_in,
                              void* d_out, int out_size, void* d_ws, size_t ws_size,
                              hipStream_t stream) {
    const float* x = (const float*)d_in[0];
    unsigned short* ws = (unsigned short*)d_ws;

    // accb = 128*SP blocks x 256x128 bf16; Lpart = 128*SP x 128 f32
    const size_t accb_us_per_sp = 128ull * CIN * QBLK;          // ushorts
    const size_t lpart_f_per_sp = 128ull * QBLK;                // floats
    size_t needed2 = (size_t)PROJ_USHORTS * 2 + 2 * accb_us_per_sp * 2 + 2 * lpart_f_per_sp * 4;
    int SP = (ws_size >= needed2) ? 2 : 1;

    unsigned short* accb = ws + PROJ_USHORTS;
    unsigned short* Wb   = accb;   // overlap: consumed by proj before attn writes accb
    float* Lpart = (float*)(ws + PROJ_USHORTS + (size_t)SP * accb_us_per_sp);

    castw_kernel<<<160, 256, 0, stream>>>(
        (const float*)d_in[1], (const float*)d_in[3], (const float*)d_in[5],
        (const float*)d_in[7], (const float*)d_in[9], (const float*)d_in[11], Wb);

    proj_kernel<<<256, 512, 0, stream>>>(
        x, Wb,
        (const float*)d_in[2],  (const float*)d_in[4],  (const float*)d_in[6],
        (const float*)d_in[8],  (const float*)d_in[10], (const float*)d_in[12],
        ws);

    attn_kernel<<<128 * SP, 512, 0, stream>>>(ws, accb, Lpart, SP);

    combine_kernel<<<2048, 256, 0, stream>>>(
        x, accb, Lpart,
        (const float*)d_in[13], (const float*)d_in[14],
        (float*)d_out, SP);
}

// Round 7
// 236.361 us; speedup vs baseline: 1.3513x; 1.3513x over previous
//
#include <hip/hip_runtime.h>

#define N 8192
#define CIN 256
#define C8 32
#define QBLK 128
#define KVB 64
#define L2E 1.4426950408889634f

typedef __attribute__((ext_vector_type(8))) short short8;   // 8 x bf16 MFMA frag
typedef __attribute__((ext_vector_type(4))) float f32x4;
typedef __attribute__((ext_vector_type(4))) float float4_;
typedef __attribute__((ext_vector_type(4))) unsigned short ushort4_;
typedef __attribute__((ext_vector_type(2))) unsigned uint2_;

// ---- ws layout (ushort units) ----
#define OFF_QTA 0u
#define OFF_KTA 262144u
#define OFF_QTB 524288u
#define OFF_KTB 786432u
#define OFF_VA  1048576u
#define OFF_VB  3145728u
#define PROJ_USHORTS 5242880u
// Wb (640x256 bf16) overlaps accb start: castW->proj read it, attn then clobbers.
// accb bf16 [2*64*SP blocks][256][128]; Lpart f32 [2*64*SP][128] after accb.

__device__ __forceinline__ unsigned short f2bf(float f) {
    unsigned u = __builtin_bit_cast(unsigned, f);
    u += 0x7fffu + ((u >> 16) & 1u);           // RNE
    return (unsigned short)(u >> 16);
}
__device__ __forceinline__ unsigned packbf2(float a, float b) {
    return (unsigned)f2bf(a) | ((unsigned)f2bf(b) << 16);
}
__device__ __forceinline__ float bf2f(unsigned short u) {
    return __builtin_bit_cast(float, (unsigned)u << 16);
}

// ---------------- castW: f32 W -> bf16 Wb[640][256], Q rows scaled by log2e ----------------
__global__ __launch_bounds__(256) void castw_kernel(
    const float* __restrict__ WqA, const float* __restrict__ WkA, const float* __restrict__ WvA,
    const float* __restrict__ WqB, const float* __restrict__ WkB, const float* __restrict__ WvB,
    unsigned short* __restrict__ Wb)
{
    const int idx = blockIdx.x * 256 + threadIdx.x;
    const int e = idx * 4;
    const int r = e >> 8;
    const float* src; int rel;
    if (r < 32)       { src = WqA; rel = e; }
    else if (r < 64)  { src = WkA; rel = e - 32 * 256; }
    else if (r < 320) { src = WvA; rel = e - 64 * 256; }
    else if (r < 352) { src = WqB; rel = e - 320 * 256; }
    else if (r < 384) { src = WkB; rel = e - 352 * 256; }
    else              { src = WvB; rel = e - 384 * 256; }
    const float sc = (r < 32 || (r >= 320 && r < 352)) ? L2E : 1.0f;
    float4_ v = *(const float4_*)(src + rel);
    ushort4_ o;
    o.x = f2bf(v.x * sc); o.y = f2bf(v.y * sc); o.z = f2bf(v.z * sc); o.w = f2bf(v.w * sc);
    *(ushort4_*)(Wb + e) = o;
}

// ---------------- projection via MFMA ----------------
__global__ __launch_bounds__(512) void proj_kernel(
    const float* __restrict__ x, const unsigned short* __restrict__ Wb,
    const float* __restrict__ bqA, const float* __restrict__ bkA, const float* __restrict__ bvA,
    const float* __restrict__ bqB, const float* __restrict__ bkB, const float* __restrict__ bvB,
    unsigned short* __restrict__ ws)
{
    __shared__ __align__(16) unsigned short xT[32 * 256];   // 16 KB

    const int tid = threadIdx.x;
    const int w = tid >> 6, l = tid & 63, g = l >> 4, lc = l & 15;
    const int n0 = blockIdx.x * 32;

    #pragma unroll
    for (int r = 0; r < 4; ++r) {
        const int flat4 = r * 512 + tid;
        const int c = flat4 >> 3, nl = (flat4 & 7) * 4;
        float4_ v = *(const float4_*)(x + (size_t)c * N + n0 + nl);
        #pragma unroll
        for (int e = 0; e < 4; ++e) {
            const int nn = nl + e;
            const int byte = nn * 512 + ((2 * c) ^ ((nn & 7) << 4));
            *(unsigned short*)((char*)xT + byte) = f2bf(v[e]);
        }
    }
    __syncthreads();

    f32x4 acc[5][2];
    #pragma unroll
    for (int i = 0; i < 5; ++i)
        #pragma unroll
        for (int ns = 0; ns < 2; ++ns) acc[i][ns] = (f32x4){0.f, 0.f, 0.f, 0.f};

    for (int c0 = 0; c0 < 256; c0 += 32) {
        short8 xf[2];
        #pragma unroll
        for (int ns = 0; ns < 2; ++ns) {
            const int byte = (ns * 16 + lc) * 512 + ((2 * (c0 + 8 * g)) ^ ((lc & 7) << 4));
            xf[ns] = *(const short8*)((const char*)xT + byte);
        }
        #pragma unroll
        for (int i = 0; i < 5; ++i) {
            const int ot = w * 5 + i;
            const short8 wf = *(const short8*)(Wb + (size_t)(ot * 16 + lc) * 256 + c0 + 8 * g);
            const bool isV = (ot >= 4 && ot < 20) || (ot >= 24);
            #pragma unroll
            for (int ns = 0; ns < 2; ++ns)
                acc[i][ns] = isV
                    ? __builtin_amdgcn_mfma_f32_16x16x32_bf16(xf[ns], wf, acc[i][ns], 0, 0, 0)
                    : __builtin_amdgcn_mfma_f32_16x16x32_bf16(wf, xf[ns], acc[i][ns], 0, 0, 0);
        }
    }

    #pragma unroll
    for (int i = 0; i < 5; ++i) {
        const int ot = w * 5 + i;
        const float* bias; unsigned short* dst; int orelm; bool isV = false; float bsc = 1.0f;
        if (ot < 2)       { bias = bqA; dst = ws + OFF_QTA; orelm = ot * 16;        bsc = L2E; }
        else if (ot < 4)  { bias = bkA; dst = ws + OFF_KTA; orelm = (ot - 2) * 16; }
        else if (ot < 20) { bias = bvA; dst = ws + OFF_VA;  orelm = (ot - 4) * 16;  isV = true; }
        else if (ot < 22) { bias = bqB; dst = ws + OFF_QTB; orelm = (ot - 20) * 16; bsc = L2E; }
        else if (ot < 24) { bias = bkB; dst = ws + OFF_KTB; orelm = (ot - 22) * 16; }
        else              { bias = bvB; dst = ws + OFF_VB;  orelm = (ot - 24) * 16; isV = true; }

        if (isV) {
            const float b = bias[orelm + lc];
            #pragma unroll
            for (int ns = 0; ns < 2; ++ns) {
                ushort4_ pk;
                pk.x = f2bf(acc[i][ns][0] + b); pk.y = f2bf(acc[i][ns][1] + b);
                pk.z = f2bf(acc[i][ns][2] + b); pk.w = f2bf(acc[i][ns][3] + b);
                *(ushort4_*)(dst + (size_t)(orelm + lc) * N + n0 + ns * 16 + 4 * g) = pk;
            }
        } else {
            #pragma unroll
            for (int ns = 0; ns < 2; ++ns) {
                ushort4_ pk;
                #pragma unroll
                for (int ii = 0; ii < 4; ++ii)
                    pk[ii] = f2bf(acc[i][ns][ii] + bias[orelm + 4 * g + ii] * bsc);
                *(ushort4_*)(dst + (size_t)(n0 + ns * 16 + lc) * C8 + orelm + 4 * g) = pk;
            }
        }
    }
}

// ---------------- fused flash-attention v4 ----------------
// grid 2*64*SP (SP=2 -> 256 = 1 block/CU), 512 thr (8 waves). QBLK=128, wave tile 64q x 64c.
// All 8 waves: S^T+softmax for own 16 cols [16w,+16) -> P LDS (swizzled, dbuf).
// PV: q-half qh=w&1 (4 q-tiles), c-quarter cs=w>>1 (4 c-tiles); V via DMA-staged LDS (dbuf).
__global__ __launch_bounds__(512) void attn_kernel(
    const unsigned short* __restrict__ ws,
    unsigned short* __restrict__ accb,
    float* __restrict__ Lpart,
    int SP)
{
    __shared__ __align__(16) unsigned short Vt[2][256 * KVB];    // 2 x 32 KB
    __shared__ __align__(16) unsigned short Pl[2][QBLK * KVB];   // 2 x 16 KB

    const int tid = threadIdx.x;
    const int w = tid >> 6, l = tid & 63, g = l >> 4, lc = l & 15;
    const int bid = blockIdx.x;
    const int dir = bid & 1;            // 1: (QA,KB,VB)->task1@0 ; 0: (QB,KA,VA)->task2@CIN*N
    const int qb  = (bid >> 1) & 63;
    const int sp  = bid >> 7;
    const int mlen = N / SP, m_base = sp * mlen, NS = mlen / KVB;

    const unsigned short* qt = ws + (dir ? OFF_QTA : OFF_QTB);
    const unsigned short* kt = ws + (dir ? OFF_KTB : OFF_KTA);
    const unsigned short* V  = ws + (dir ? OFF_VB  : OFF_VA);

    const int q0  = qb * QBLK;
    const int myq = w * 16 + lc;        // this wave's softmax col (local, 8 waves cover 128)
    const int qh  = w & 1;              // q-half for PV (4 q-tiles)
    const int cs  = w >> 1;             // c-quarter for PV (4 c-tiles)
    const int sw7 = lc & 7;

    const short8 qf = *(const short8*)(qt + (size_t)(q0 + myq) * C8 + 8 * g);

    // V staging: wave w stages rows [w*32,+32). Linear dest, inverse-swizzled source.
    const int src_c   = w * 32 + (l >> 3);
    const int src_swz = ((l & 7) ^ ((l >> 3) & 7)) << 3;
    #define STAGE(vb, mo)                                                                 \
        _Pragma("unroll")                                                                 \
        for (int h = 0; h < 4; ++h) {                                                     \
            const unsigned short* srcp = V + (size_t)(src_c + 8 * h) * N + (mo) + src_swz; \
            __builtin_amdgcn_global_load_lds(                                             \
                (const __attribute__((address_space(1))) unsigned*)srcp,                  \
                (__attribute__((address_space(3))) unsigned*)(&Vt[vb][(w * 32 + h * 8) * KVB]), \
                16, 0, 0);                                                                \
        }

    STAGE(0, m_base)

    short8 kf[4], kfn[4];
    #pragma unroll
    for (int t = 0; t < 4; ++t)
        kf[t] = *(const short8*)(kt + (size_t)(m_base + 16 * t + lc) * C8 + 8 * g);

    f32x4 acc[4][4];   // [j=q-tile][u=c-tile]: D[q][c]
    #pragma unroll
    for (int j = 0; j < 4; ++j)
        #pragma unroll
        for (int u = 0; u < 4; ++u) acc[j][u] = (f32x4){0.f, 0.f, 0.f, 0.f};
    float Lr = 0.f;

    for (int s = 0; s < NS; ++s) {
        const int m0 = m_base + s * KVB;
        const int pb = s & 1;
        const bool more = (s + 1 < NS);

        if (more) {   // K prefetch (latency hidden under S+PV)
            #pragma unroll
            for (int t = 0; t < 4; ++t)
                kfn[t] = *(const short8*)(kt + (size_t)(m0 + KVB + 16 * t + lc) * C8 + 8 * g);
        }

        // ---- S phase: S^T = mfma(K,Q); P = exp2(S) (log2e folded into Wq/bq) ----
        f32x4 sv[4];
        #pragma unroll
        for (int t = 0; t < 4; ++t)
            sv[t] = __builtin_amdgcn_mfma_f32_16x16x32_bf16(kf[t], qf, (f32x4){0.f,0.f,0.f,0.f}, 0, 0, 0);

        #pragma unroll
        for (int t = 0; t < 4; ++t) {
            float p0 = __builtin_amdgcn_exp2f(sv[t][0]);
            float p1 = __builtin_amdgcn_exp2f(sv[t][1]);
            float p2 = __builtin_amdgcn_exp2f(sv[t][2]);
            float p3 = __builtin_amdgcn_exp2f(sv[t][3]);
            Lr += (p0 + p1) + (p2 + p3);
            uint2_ u2; u2.x = packbf2(p0, p1); u2.y = packbf2(p2, p3);
            // m = 16t+4g+i -> chunk 2t+(g>>1), half (g&1); swizzle chunk by q&7
            const int byte = myq * 128 + (((2 * t + (g >> 1)) ^ sw7) << 4) + ((g & 1) << 3);
            *(uint2_*)((char*)Pl[pb] + byte) = u2;
        }

        __syncthreads();   // P[pb] visible; V[pb] DMA (issued last step) drained

        if (more) STAGE(pb ^ 1, m0 + KVB)   // full-step drain window (next barrier)

        // ---- PV phase: acc[q][c] += P(as A) x V^T(as B) ----
        __builtin_amdgcn_s_setprio(1);
        short8 vf[4][2];
        #pragma unroll
        for (int u = 0; u < 4; ++u)
            #pragma unroll
            for (int kc = 0; kc < 2; ++kc)
                vf[u][kc] = *(const short8*)((const char*)Vt[pb]
                              + ((cs * 4 + u) * 16 + lc) * 128 + (((kc * 4 + g) ^ sw7) << 4));
        #pragma unroll
        for (int kc = 0; kc < 2; ++kc) {
            #pragma unroll
            for (int j = 0; j < 4; ++j) {
                const short8 pf = *(const short8*)((const char*)Pl[pb]
                              + ((qh * 4 + j) * 16 + lc) * 128 + (((kc * 4 + g) ^ sw7) << 4));
                #pragma unroll
                for (int u = 0; u < 4; ++u)
                    acc[j][u] = __builtin_amdgcn_mfma_f32_16x16x32_bf16(pf, vf[u][kc], acc[j][u], 0, 0, 0);
            }
        }
        __builtin_amdgcn_s_setprio(0);

        if (more) {
            #pragma unroll
            for (int t = 0; t < 4; ++t) kf[t] = kfn[t];
        }
    }

    // ---- epilogue: Lr covers this wave's 16 S-cols; partials to accb[c][q] ----
    Lr += __shfl_xor(Lr, 16);
    Lr += __shfl_xor(Lr, 32);

    const size_t blk = (size_t)(dir * 64 + qb) * SP + sp;
    unsigned short* ab = accb + blk * (size_t)(CIN * QBLK);
    #pragma unroll
    for (int j = 0; j < 4; ++j)
        #pragma unroll
        for (int u = 0; u < 4; ++u) {
            const int c    = (cs * 4 + u) * 16 + lc;
            const int qloc = (qh * 4 + j) * 16 + 4 * g;
            ushort4_ pk;
            pk.x = f2bf(acc[j][u][0]); pk.y = f2bf(acc[j][u][1]);
            pk.z = f2bf(acc[j][u][2]); pk.w = f2bf(acc[j][u][3]);
            *(ushort4_*)(ab + (size_t)c * QBLK + qloc) = pk;
        }
    if (l < 16) Lpart[blk * QBLK + w * 16 + l] = Lr;
}

// ---------------- combine: out = gamma * (sum acc)/(sum L) + x ----------------
__global__ __launch_bounds__(256) void combine_kernel(
    const float* __restrict__ x,
    const unsigned short* __restrict__ accb,
    const float* __restrict__ Lpart,
    const float* __restrict__ gammaA, const float* __restrict__ gammaB,
    float* __restrict__ out, int SP)
{
    const int tid = blockIdx.x * 256 + threadIdx.x;    // 2^19 threads x 8 elems
    const int nl0 = (tid & 15) * 8;
    const int qb  = (tid >> 4) & 63;
    const int c   = (tid >> 10) & 255;
    const int dir = (tid >> 18) & 1;

    const size_t bb = (size_t)(dir * 64 + qb) * SP;
    float s[8], Ls[8];
    #pragma unroll
    for (int e = 0; e < 8; ++e) { s[e] = 0.f; Ls[e] = 0.f; }

    for (int sp = 0; sp < SP; ++sp) {
        const unsigned short* ap = accb + (bb + sp) * (size_t)(CIN * QBLK) + (size_t)c * QBLK + nl0;
        const short8 av = *(const short8*)ap;
        const float* lp = Lpart + (bb + sp) * QBLK + nl0;
        #pragma unroll
        for (int e = 0; e < 8; ++e) {
            s[e]  += bf2f((unsigned short)av[e]);
            Ls[e] += lp[e];
        }
    }

    const float gamma = dir ? gammaA[0] : gammaB[0];
    const size_t off = (size_t)c * N + qb * QBLK + nl0;
    const float* xp = x + off;
    float* op = out + (dir ? 0 : (size_t)CIN * N) + off;
    #pragma unroll
    for (int e = 0; e < 8; ++e) op[e] = gamma * s[e] / Ls[e] + xp[e];
}

extern "C" void kernel_launch(void* const* d_in, const int* in_sizes, int n_in,
                              void* d_out, int out_size, void* d_ws, size_t ws_size,
                              hipStream_t stream) {
    const float* x = (const float*)d_in[0];
    unsigned short* ws = (unsigned short*)d_ws;

    const size_t accb_us_per_sp = 128ull * CIN * QBLK;          // ushorts
    const size_t lpart_f_per_sp = 128ull * QBLK;                // floats
    size_t needed2 = (size_t)PROJ_USHORTS * 2 + 2 * accb_us_per_sp * 2 + 2 * lpart_f_per_sp * 4;
    int SP = (ws_size >= needed2) ? 2 : 1;

    unsigned short* accb = ws + PROJ_USHORTS;
    unsigned short* Wb   = accb;   // overlap: consumed by proj before attn writes accb
    float* Lpart = (float*)(ws + PROJ_USHORTS + (size_t)SP * accb_us_per_sp);

    castw_kernel<<<160, 256, 0, stream>>>(
        (const float*)d_in[1], (const float*)d_in[3], (const float*)d_in[5],
        (const float*)d_in[7], (const float*)d_in[9], (const float*)d_in[11], Wb);

    proj_kernel<<<256, 512, 0, stream>>>(
        x, Wb,
        (const float*)d_in[2],  (const float*)d_in[4],  (const float*)d_in[6],
        (const float*)d_in[8],  (const float*)d_in[10], (const float*)d_in[12],
        ws);

    attn_kernel<<<128 * SP, 512, 0, stream>>>(ws, accb, Lpart, SP);

    combine_kernel<<<2048, 256, 0, stream>>>(
        x, accb, Lpart,
        (const float*)d_in[13], (const float*)d_in[14],
        (float*)d_out, SP);
}